// Round 3
// baseline (232.583 us; speedup 1.0000x reference)
//
#include <hip/hip_runtime.h>
#include <hip/hip_bf16.h>

typedef __hip_bfloat16 bf16;
typedef float in_t;
typedef float out_t;

#define CH    64
#define CIN1  32
#define CIN2  64
#define S1    186624   // 36*72*72
#define W1    5184     // 72*72
#define S2    23328    // 18*36*36
#define W2    1296     // 36*36
#define LDSTR 1297     // k_M LDS row stride (1297%32=17, coprime -> conflict-free)
#define MSTR  84       // k_corr padded stride (mult of 4 -> float4-aligned rows)
#define INV_NZ (1.0f/(288.0f + 1e-5f))

static __device__ __forceinline__ float b2f(bf16 v){ return __bfloat162float(v); }

// ---- xq[o,s] = b[o] + sum_c w[o,c]*x[c,s]  (bf16 store; weights via scalar loads)
__global__ __launch_bounds__(256) void k_proj_x(
    const in_t* __restrict__ x, const in_t* __restrict__ w, const in_t* __restrict__ bias,
    bf16* __restrict__ xq)
{
    int s = blockIdx.x*256 + threadIdx.x;
    float xv[CIN1];
    #pragma unroll
    for (int c = 0; c < CIN1; ++c) xv[c] = x[c*S1 + s];
    #pragma unroll 4
    for (int o = 0; o < CH; ++o) {
        float acc = bias[o];                  // uniform -> s_load
        #pragma unroll
        for (int c = 0; c < CIN1; ++c)
            acc += w[o*CIN1 + c] * xv[c];     // uniform -> s_load
        xq[o*S1 + s] = __float2bfloat16(acc);
    }
}

// ---- yk[o,s] = b[o] + sum_c w[o,c]*y[c,s]  (fp32 store, small tensor)
__global__ __launch_bounds__(256) void k_proj_y(
    const in_t* __restrict__ y, const in_t* __restrict__ w, const in_t* __restrict__ bias,
    float* __restrict__ yk)
{
    int s = blockIdx.x*256 + threadIdx.x;
    if (s >= S2) return;
    float yv[CIN2];
    #pragma unroll
    for (int c = 0; c < CIN2; ++c) yv[c] = y[c*S2 + s];
    #pragma unroll 4
    for (int o = 0; o < CH; ++o) {
        float acc = bias[o];
        #pragma unroll
        for (int c = 0; c < CIN2; ++c)
            acc += w[o*CIN2 + c] * yv[c];
        yk[o*S2 + s] = acc;
    }
}

// ---- AvgPool3d k3 s2 p1 count_include_pad=False: z(64,36,72,72) -> xd(64,18,36,36)
__global__ __launch_bounds__(256) void k_pool(const in_t* __restrict__ z, float* __restrict__ xd)
{
    int idx = blockIdx.x*256 + threadIdx.x;   // 64*23328 total, exact grid
    int c  = idx / S2;
    int r  = idx - c*S2;
    int od = r / W2;
    int r2 = r - od*W2;
    int oh = r2 / 36;
    int ow = r2 - oh*36;
    int dlo = max(2*od-1, 0), dhi = min(2*od+1, 35);
    int hlo = max(2*oh-1, 0), hhi = min(2*oh+1, 71);
    int wlo = max(2*ow-1, 0), whi = min(2*ow+1, 71);
    int cnt = (dhi-dlo+1)*(hhi-hlo+1)*(whi-wlo+1);
    const in_t* zc = z + c*S1;
    float s = 0.f;
    for (int d = dlo; d <= dhi; ++d)
        for (int h = hlo; h <= hhi; ++h)
            for (int w = wlo; w <= whi; ++w)
                s += zc[d*W1 + h*72 + w];
    xd[idx] = s / (float)cnt;
}

// ---- M[c,k1,k2] = sum_m Uxd[c,k1,m]*Uy[c,k2,m]
__global__ __launch_bounds__(256) void k_M(
    const float* __restrict__ xd, const float* __restrict__ yk, float* __restrict__ Mout)
{
    __shared__ float ylds[9*LDSTR];
    __shared__ float xlds[3*LDSTR];
    int c = blockIdx.x / 3, g = blockIdx.x - (blockIdx.x/3)*3;
    int t = threadIdx.x;
    int t1 = t / 27, t2 = t - (t/27)*27;
    int offx[3], offy[3];
    #pragma unroll
    for (int a = 0; a < 3; ++a) {
        int l1 = t1*3 + a;
        offx[a] = (l1/9)*LDSTR + (l1 - (l1/9)*9);
    }
    #pragma unroll
    for (int b = 0; b < 3; ++b) {
        int k2 = t2*3 + b;
        offy[b] = (k2/9)*LDSTR + (k2 - (k2/9)*9);
    }
    float acc[3][3] = {};
    for (int ph2 = 0; ph2 < 2; ++ph2) {
        __syncthreads();
        for (int idx = t; idx < 9*W2; idx += 256) {
            int rr = idx / W2, col = idx - rr*W2;
            ylds[rr*LDSTR + col] = yk[c*S2 + (ph2*9 + rr)*W2 + col];
        }
        for (int idx = t; idx < 3*W2; idx += 256) {
            int rr = idx / W2, col = idx - rr*W2;
            xlds[rr*LDSTR + col] = xd[c*S2 + (ph2*9 + g*3 + rr)*W2 + col];
        }
        __syncthreads();
        if (t < 243) {
            for (int pw2 = 0; pw2 < 144; ++pw2) {
                int cb = pw2*9;
                float xv[3], yv[3];
                #pragma unroll
                for (int a = 0; a < 3; ++a) xv[a] = xlds[cb + offx[a]];
                #pragma unroll
                for (int b = 0; b < 3; ++b) yv[b] = ylds[cb + offy[b]];
                #pragma unroll
                for (int a = 0; a < 3; ++a)
                    #pragma unroll
                    for (int b = 0; b < 3; ++b) acc[a][b] += xv[a]*yv[b];
            }
        }
    }
    if (t < 243) {
        #pragma unroll
        for (int a = 0; a < 3; ++a) {
            int k1 = g*27 + t1*3 + a;
            #pragma unroll
            for (int b = 0; b < 3; ++b)
                Mout[c*6561 + k1*81 + (t2*3 + b)] = acc[a][b];
        }
    }
}

// ---- corr = (M @ Ux)/nz, fold9, LeakyReLU(0.2), out = dec*(1+act)
// grid = 64 ch * 4 ph * 16 groups of 36 patches; 243 active threads, 3x4 tiles, float4 LDS
__global__ __launch_bounds__(256) void k_corr(
    const float* __restrict__ M, const bf16* __restrict__ xq,
    const in_t* __restrict__ z, out_t* __restrict__ out)
{
    __shared__ __align__(16) float Mlds[81*MSTR];
    __shared__ __align__(16) float plds[36*MSTR];
    int bid = blockIdx.x;
    int c   = bid >> 6;
    int rem = bid & 63;
    int ph  = rem >> 4;
    int grp = rem & 15;
    int colbase = grp*324;          // 36 patches * 9 cols
    int t = threadIdx.x;
    for (int idx = t; idx < 6561; idx += 256) {
        int k1 = idx / 81, k2 = idx - k1*81;
        Mlds[k1*MSTR + k2] = M[c*6561 + idx];
    }
    // coalesced xq staging: i2-major (contiguous 648B rows)
    for (int idx = t; idx < 2916; idx += 256) {
        int i2 = idx / 324, col = idx - i2*324;
        int p = col / 9, j2 = col - p*9;
        plds[p*MSTR + i2*9 + j2] = b2f(xq[c*S1 + (ph*9 + i2)*W1 + colbase + col]);
    }
    __syncthreads();
    float acc[3][4] = {};
    int kt = t % 27, pt = t / 27;
    if (t < 243) {
        const float4* M0 = (const float4*)&Mlds[(kt*3 + 0)*MSTR];
        const float4* M1 = (const float4*)&Mlds[(kt*3 + 1)*MSTR];
        const float4* M2 = (const float4*)&Mlds[(kt*3 + 2)*MSTR];
        const float4* P0 = (const float4*)&plds[(pt*4 + 0)*MSTR];
        const float4* P1 = (const float4*)&plds[(pt*4 + 1)*MSTR];
        const float4* P2 = (const float4*)&plds[(pt*4 + 2)*MSTR];
        const float4* P3 = (const float4*)&plds[(pt*4 + 3)*MSTR];
        #pragma unroll 4
        for (int q = 0; q < 20; ++q) {
            float4 mv[3] = { M0[q], M1[q], M2[q] };
            float4 xv[4] = { P0[q], P1[q], P2[q], P3[q] };
            #pragma unroll
            for (int a = 0; a < 3; ++a) {
                #pragma unroll
                for (int b = 0; b < 4; ++b) {
                    acc[a][b] += mv[a].x*xv[b].x + mv[a].y*xv[b].y
                               + mv[a].z*xv[b].z + mv[a].w*xv[b].w;
                }
            }
        }
        // tail k2 = 80
        float mt[3], xt[4];
        #pragma unroll
        for (int a = 0; a < 3; ++a) mt[a] = Mlds[(kt*3 + a)*MSTR + 80];
        #pragma unroll
        for (int b = 0; b < 4; ++b) xt[b] = plds[(pt*4 + b)*MSTR + 80];
        #pragma unroll
        for (int a = 0; a < 3; ++a)
            #pragma unroll
            for (int b = 0; b < 4; ++b) acc[a][b] += mt[a]*xt[b];
    }
    __syncthreads();
    if (t < 243) {
        #pragma unroll
        for (int b = 0; b < 4; ++b)
            #pragma unroll
            for (int a = 0; a < 3; ++a)
                plds[(pt*4 + b)*81 + kt*3 + a] = acc[a][b];   // reuse as out staging
    }
    __syncthreads();
    for (int idx = t; idx < 2916; idx += 256) {
        int i = idx / 324, cc = idx - i*324;
        int p = cc / 9,   j  = cc - p*9;
        float corr = plds[p*81 + i*9 + j] * INV_NZ;
        float act  = corr > 0.f ? corr : 0.2f*corr;
        int ga = c*S1 + (ph*9 + i)*W1 + colbase + cc;
        float dec = z[ga];
        out[ga] = dec + act*dec;
    }
}

extern "C" void kernel_launch(void* const* d_in, const int* in_sizes, int n_in,
                              void* d_out, int out_size, void* d_ws, size_t ws_size,
                              hipStream_t stream)
{
    (void)in_sizes; (void)n_in; (void)out_size; (void)ws_size;
    const in_t* x     = (const in_t*)d_in[0];
    const in_t* y     = (const in_t*)d_in[1];
    const in_t* z     = (const in_t*)d_in[2];
    const in_t* w_img = (const in_t*)d_in[3];
    const in_t* b_img = (const in_t*)d_in[4];
    const in_t* w_fea = (const in_t*)d_in[5];
    const in_t* b_fea = (const in_t*)d_in[6];
    out_t* out = (out_t*)d_out;

    char* ws = (char*)d_ws;
    bf16*  xq  = (bf16*) (ws + 0);          // 64*186624*2 = 23,887,872
    float* yk  = (float*)(ws + 23887872);   // 64*23328*4  =  5,971,968
    float* xd  = (float*)(ws + 29859840);   // 64*23328*4  =  5,971,968
    float* Mb  = (float*)(ws + 35831808);   // 64*6561*4   =  1,679,616

    hipLaunchKernelGGL(k_proj_x,  dim3(S1/256),       dim3(256), 0, stream, x, w_img, b_img, xq);
    hipLaunchKernelGGL(k_proj_y,  dim3((S2+255)/256), dim3(256), 0, stream, y, w_fea, b_fea, yk);
    hipLaunchKernelGGL(k_pool,    dim3((CH*S2)/256),  dim3(256), 0, stream, z, xd);
    hipLaunchKernelGGL(k_M,       dim3(192),          dim3(256), 0, stream, xd, yk, Mb);
    hipLaunchKernelGGL(k_corr,    dim3(4096),         dim3(256), 0, stream, Mb, xq, z, out);
}

// Round 4
// 150.504 us; speedup vs baseline: 1.5454x; 1.5454x over previous
//
#include <hip/hip_runtime.h>
#include <hip/hip_bf16.h>

typedef __hip_bfloat16 bf16;
typedef float in_t;
typedef float out_t;
typedef __attribute__((ext_vector_type(8))) short short8;   // 8 bf16 MFMA operand
typedef __attribute__((ext_vector_type(4))) float f32x4;    // MFMA accumulator

#define CH    64
#define CIN1  32
#define CIN2  64
#define S1    186624   // 36*72*72
#define W1    5184     // 72*72
#define S2    23328    // 18*36*36
#define W2    1296     // 36*36
#define LDSTR 1297     // k_M LDS row stride (coprime with 32)
#define ASTR  104      // Mlds bf16 row stride (104*2=208B, 52 dwords, gcd(52,32)=4 -> 8-bank spread)
#define BSTR  104      // patch lds bf16 row stride
#define INV_NZ (1.0f/(288.0f + 1e-5f))

static __device__ __forceinline__ unsigned short f2bu(float f) {
    bf16 h = __float2bfloat16(f);
    unsigned short u;
    __builtin_memcpy(&u, &h, 2);
    return u;
}

// ---- xq[o,s] = b[o] + sum_c w[o,c]*x[c,s]  (bf16 store; weights via scalar loads)
__global__ __launch_bounds__(256) void k_proj_x(
    const in_t* __restrict__ x, const in_t* __restrict__ w, const in_t* __restrict__ bias,
    bf16* __restrict__ xq)
{
    int s = blockIdx.x*256 + threadIdx.x;
    float xv[CIN1];
    #pragma unroll
    for (int c = 0; c < CIN1; ++c) xv[c] = x[c*S1 + s];
    #pragma unroll 4
    for (int o = 0; o < CH; ++o) {
        float acc = bias[o];
        #pragma unroll
        for (int c = 0; c < CIN1; ++c)
            acc += w[o*CIN1 + c] * xv[c];
        xq[o*S1 + s] = __float2bfloat16(acc);
    }
}

// ---- yk: 512 blocks = 32 o-pairs x 16 spatial chunks of 1458
__global__ __launch_bounds__(256) void k_proj_y(
    const in_t* __restrict__ y, const in_t* __restrict__ w, const in_t* __restrict__ bias,
    float* __restrict__ yk)
{
    int bid   = blockIdx.x;
    int o0    = (bid >> 4) * 2;
    int chunk = bid & 15;
    int t = threadIdx.x;
    float b0 = bias[o0], b1 = bias[o0+1];
    for (int it = 0; it < 6; ++it) {
        int sl = it*256 + t;
        if (sl >= 1458) break;
        int s = chunk*1458 + sl;
        float a0 = b0, a1 = b1;
        #pragma unroll
        for (int cc = 0; cc < CIN2; ++cc) {
            float yv = y[cc*S2 + s];
            a0 += w[o0*CIN2 + cc]     * yv;
            a1 += w[(o0+1)*CIN2 + cc] * yv;
        }
        yk[o0*S2 + s]     = a0;
        yk[(o0+1)*S2 + s] = a1;
    }
}

// ---- AvgPool3d k3 s2 p1 count_include_pad=False: z(64,36,72,72) -> xd(64,18,36,36)
__global__ __launch_bounds__(256) void k_pool(const in_t* __restrict__ z, float* __restrict__ xd)
{
    int idx = blockIdx.x*256 + threadIdx.x;
    int c  = idx / S2;
    int r  = idx - c*S2;
    int od = r / W2;
    int r2 = r - od*W2;
    int oh = r2 / 36;
    int ow = r2 - oh*36;
    int dlo = max(2*od-1, 0), dhi = min(2*od+1, 35);
    int hlo = max(2*oh-1, 0), hhi = min(2*oh+1, 71);
    int wlo = max(2*ow-1, 0), whi = min(2*ow+1, 71);
    int cnt = (dhi-dlo+1)*(hhi-hlo+1)*(whi-wlo+1);
    const in_t* zc = z + c*S1;
    float s = 0.f;
    for (int d = dlo; d <= dhi; ++d)
        for (int h = hlo; h <= hhi; ++h)
            for (int w = wlo; w <= whi; ++w)
                s += zc[d*W1 + h*72 + w];
    xd[idx] = s / (float)cnt;
}

// ---- M[c,k1,k2] = sum_m Uxd[c,k1,m]*Uy[c,k2,m]
__global__ __launch_bounds__(256) void k_M(
    const float* __restrict__ xd, const float* __restrict__ yk, float* __restrict__ Mout)
{
    __shared__ float ylds[9*LDSTR];
    __shared__ float xlds[3*LDSTR];
    int c = blockIdx.x / 3, g = blockIdx.x - (blockIdx.x/3)*3;
    int t = threadIdx.x;
    int t1 = t / 27, t2 = t - (t/27)*27;
    int offx[3], offy[3];
    #pragma unroll
    for (int a = 0; a < 3; ++a) {
        int l1 = t1*3 + a;
        offx[a] = (l1/9)*LDSTR + (l1 - (l1/9)*9);
    }
    #pragma unroll
    for (int b = 0; b < 3; ++b) {
        int k2 = t2*3 + b;
        offy[b] = (k2/9)*LDSTR + (k2 - (k2/9)*9);
    }
    float acc[3][3] = {};
    for (int ph2 = 0; ph2 < 2; ++ph2) {
        __syncthreads();
        for (int idx = t; idx < 9*W2; idx += 256) {
            int rr = idx / W2, col = idx - rr*W2;
            ylds[rr*LDSTR + col] = yk[c*S2 + (ph2*9 + rr)*W2 + col];
        }
        for (int idx = t; idx < 3*W2; idx += 256) {
            int rr = idx / W2, col = idx - rr*W2;
            xlds[rr*LDSTR + col] = xd[c*S2 + (ph2*9 + g*3 + rr)*W2 + col];
        }
        __syncthreads();
        if (t < 243) {
            for (int pw2 = 0; pw2 < 144; ++pw2) {
                int cb = pw2*9;
                float xv[3], yv[3];
                #pragma unroll
                for (int a = 0; a < 3; ++a) xv[a] = xlds[cb + offx[a]];
                #pragma unroll
                for (int b = 0; b < 3; ++b) yv[b] = ylds[cb + offy[b]];
                #pragma unroll
                for (int a = 0; a < 3; ++a)
                    #pragma unroll
                    for (int b = 0; b < 3; ++b) acc[a][b] += xv[a]*yv[b];
            }
        }
    }
    if (t < 243) {
        #pragma unroll
        for (int a = 0; a < 3; ++a) {
            int k1 = g*27 + t1*3 + a;
            #pragma unroll
            for (int b = 0; b < 3; ++b)
                Mout[c*6561 + k1*81 + (t2*3 + b)] = acc[a][b];
        }
    }
}

// ---- MFMA corr: per (channel, 192-patch chunk): C(96x192) = Mbf16(96x96) x Uxq^T(96x192)
// grid = 64ch * 4ph * 3ck = 768 blocks, 256 threads (4 waves)
__global__ __launch_bounds__(256) void k_corr(
    const float* __restrict__ M, const bf16* __restrict__ xq,
    const in_t* __restrict__ z, out_t* __restrict__ out)
{
    __shared__ __align__(16) unsigned short Ml[96*ASTR];
    __shared__ __align__(16) unsigned short Pl[192*BSTR];
    int bid = blockIdx.x;
    int c   = bid / 12;
    int rem = bid - c*12;
    int ph  = rem / 3;
    int ck  = rem - ph*3;
    int colbase = ck*1728;
    int t = threadIdx.x;

    // zero pads (disjoint from data fills -> no barrier needed between them)
    for (int idx = t; idx < 81*23; idx += 256) {
        int r = idx/23;
        Ml[r*ASTR + 81 + (idx - r*23)] = 0;
    }
    for (int idx = t; idx < 15*ASTR; idx += 256)
        Ml[81*ASTR + idx] = 0;
    for (int idx = t; idx < 192*23; idx += 256) {
        int r = idx/23;
        Pl[r*BSTR + 81 + (idx - r*23)] = 0;
    }
    // stage M (fp32 -> bf16), rows k1, cols k2
    for (int idx = t; idx < 6561; idx += 256) {
        int k1 = idx/81, k2 = idx - k1*81;
        Ml[k1*ASTR + k2] = f2bu(M[c*6561 + idx]);
    }
    // stage xq chunk: 9 rows x 1728 cols -> Pl[patch][i2*9+j2]
    const unsigned short* xqu =
        (const unsigned short*)(xq + (size_t)c*S1 + (size_t)(ph*9)*W1 + colbase);
    for (int idx = t; idx < 3888; idx += 256) {    // 9*432 ushort4 loads
        int i2 = idx / 432, v4 = idx - i2*432;
        ushort4 vv = *reinterpret_cast<const ushort4*>(xqu + (size_t)i2*W1 + v4*4);
        int col = v4*4;
        unsigned short uu[4] = {vv.x, vv.y, vv.z, vv.w};
        #pragma unroll
        for (int j = 0; j < 4; ++j) {
            int cc = col + j;
            int p = cc/9, j2 = cc - p*9;
            Pl[p*BSTR + i2*9 + j2] = uu[j];
        }
    }
    __syncthreads();

    int wv = t >> 6, l = t & 63;
    int lrow = l & 15, lhi = l >> 4;

    // B fragments: wave wv owns n-tiles wv*3 .. wv*3+2 (n = patch index in chunk)
    short8 bfr[3][3];
    #pragma unroll
    for (int ntl = 0; ntl < 3; ++ntl) {
        int n = (wv*3 + ntl)*16 + lrow;
        #pragma unroll
        for (int kk = 0; kk < 3; ++kk)
            bfr[ntl][kk] = *reinterpret_cast<const short8*>(&Pl[n*BSTR + kk*32 + lhi*8]);
    }
    __syncthreads();   // all B-frags in regs before Pl is reused as staging

    f32x4 acc[6][3];
    #pragma unroll
    for (int mt = 0; mt < 6; ++mt)
        #pragma unroll
        for (int ntl = 0; ntl < 3; ++ntl)
            acc[mt][ntl] = (f32x4){0.f,0.f,0.f,0.f};

    #pragma unroll
    for (int mt = 0; mt < 6; ++mt) {
        short8 afr[3];
        int m = mt*16 + lrow;
        #pragma unroll
        for (int kk = 0; kk < 3; ++kk)
            afr[kk] = *reinterpret_cast<const short8*>(&Ml[m*ASTR + kk*32 + lhi*8]);
        #pragma unroll
        for (int ntl = 0; ntl < 3; ++ntl) {
            f32x4 d = acc[mt][ntl];
            #pragma unroll
            for (int kk = 0; kk < 3; ++kk)
                d = __builtin_amdgcn_mfma_f32_16x16x32_bf16(afr[kk], bfr[ntl][kk], d, 0, 0, 0);
            acc[mt][ntl] = d;
        }
    }
    __syncthreads();

    // epilogue: 2 passes of 96 patches via LDS staging (9 rows x 864 cols fp32 = 31KB)
    float* stage = reinterpret_cast<float*>(Pl);
    #pragma unroll
    for (int pass = 0; pass < 2; ++pass) {
        if ((wv >> 1) == pass) {
            #pragma unroll
            for (int mt = 0; mt < 6; ++mt)
                #pragma unroll
                for (int ntl = 0; ntl < 3; ++ntl) {
                    int n = (wv*3 + ntl)*16 + lrow - pass*96;   // 0..95
                    #pragma unroll
                    for (int r = 0; r < 4; ++r) {
                        int m = mt*16 + lhi*4 + r;              // k1
                        if (m <= 80) {
                            int i = m/9, j = m - 9*i;
                            stage[i*864 + n*9 + j] = acc[mt][ntl][r];
                        }
                    }
                }
        }
        __syncthreads();
        for (int idx = t; idx < 7776; idx += 256) {
            int i = idx/864, col = idx - i*864;
            int ga = c*S1 + (ph*9 + i)*W1 + colbase + pass*864 + col;
            float corr = stage[idx] * INV_NZ;
            float act  = corr > 0.f ? corr : 0.2f*corr;
            float dec  = z[ga];
            out[ga] = dec + act*dec;
        }
        __syncthreads();
    }
}

extern "C" void kernel_launch(void* const* d_in, const int* in_sizes, int n_in,
                              void* d_out, int out_size, void* d_ws, size_t ws_size,
                              hipStream_t stream)
{
    (void)in_sizes; (void)n_in; (void)out_size; (void)ws_size;
    const in_t* x     = (const in_t*)d_in[0];
    const in_t* y     = (const in_t*)d_in[1];
    const in_t* z     = (const in_t*)d_in[2];
    const in_t* w_img = (const in_t*)d_in[3];
    const in_t* b_img = (const in_t*)d_in[4];
    const in_t* w_fea = (const in_t*)d_in[5];
    const in_t* b_fea = (const in_t*)d_in[6];
    out_t* out = (out_t*)d_out;

    char* ws = (char*)d_ws;
    bf16*  xq  = (bf16*) (ws + 0);          // 64*186624*2 = 23,887,872
    float* yk  = (float*)(ws + 23887872);   // 64*23328*4
    float* xd  = (float*)(ws + 29859840);   // 64*23328*4
    float* Mb  = (float*)(ws + 35831808);   // 64*6561*4

    hipLaunchKernelGGL(k_proj_x, dim3(S1/256),      dim3(256), 0, stream, x, w_img, b_img, xq);
    hipLaunchKernelGGL(k_proj_y, dim3(512),         dim3(256), 0, stream, y, w_fea, b_fea, yk);
    hipLaunchKernelGGL(k_pool,   dim3((CH*S2)/256), dim3(256), 0, stream, z, xd);
    hipLaunchKernelGGL(k_M,      dim3(192),         dim3(256), 0, stream, xd, yk, Mb);
    hipLaunchKernelGGL(k_corr,   dim3(768),         dim3(256), 0, stream, Mb, xq, z, out);
}

// Round 5
// 134.298 us; speedup vs baseline: 1.7318x; 1.1207x over previous
//
#include <hip/hip_runtime.h>
#include <hip/hip_bf16.h>

typedef __hip_bfloat16 bf16;
typedef float in_t;
typedef float out_t;
typedef __attribute__((ext_vector_type(8))) short short8;   // 8 bf16 MFMA operand
typedef __attribute__((ext_vector_type(4))) float f32x4;    // MFMA accumulator

#define CH    64
#define CIN1  32
#define CIN2  64
#define S1    186624   // 36*72*72
#define W1    5184     // 72*72
#define S2    23328    // 18*36*36
#define W2    1296     // 36*36
#define LDSTR 1297     // k_M LDS row stride (coprime with 32)
#define BSTR  104      // patch lds bf16 row stride (208B rows; ~1.6% conflict cycles in R4)
#define INV_NZ (1.0f/(288.0f + 1e-5f))

static __device__ __forceinline__ unsigned short f2bu(float f) {
    bf16 h = __float2bfloat16(f);
    unsigned short u;
    __builtin_memcpy(&u, &h, 2);
    return u;
}

// ---- xq[o,s] = b[o] + sum_c w[o,c]*x[c,s]  (bf16 store; weights via scalar loads)
__global__ __launch_bounds__(256) void k_proj_x(
    const in_t* __restrict__ x, const in_t* __restrict__ w, const in_t* __restrict__ bias,
    bf16* __restrict__ xq)
{
    int s = blockIdx.x*256 + threadIdx.x;
    float xv[CIN1];
    #pragma unroll
    for (int c = 0; c < CIN1; ++c) xv[c] = x[c*S1 + s];
    #pragma unroll 4
    for (int o = 0; o < CH; ++o) {
        float acc = bias[o];
        #pragma unroll
        for (int c = 0; c < CIN1; ++c)
            acc += w[o*CIN1 + c] * xv[c];
        xq[o*S1 + s] = __float2bfloat16(acc);
    }
}

// ---- yk: 512 blocks = 32 o-pairs x 16 spatial chunks of 1458
__global__ __launch_bounds__(256) void k_proj_y(
    const in_t* __restrict__ y, const in_t* __restrict__ w, const in_t* __restrict__ bias,
    float* __restrict__ yk)
{
    int bid   = blockIdx.x;
    int o0    = (bid >> 4) * 2;
    int chunk = bid & 15;
    int t = threadIdx.x;
    float b0 = bias[o0], b1 = bias[o0+1];
    for (int it = 0; it < 6; ++it) {
        int sl = it*256 + t;
        if (sl >= 1458) break;
        int s = chunk*1458 + sl;
        float a0 = b0, a1 = b1;
        #pragma unroll
        for (int cc = 0; cc < CIN2; ++cc) {
            float yv = y[cc*S2 + s];
            a0 += w[o0*CIN2 + cc]     * yv;
            a1 += w[(o0+1)*CIN2 + cc] * yv;
        }
        yk[o0*S2 + s]     = a0;
        yk[(o0+1)*S2 + s] = a1;
    }
}

// ---- AvgPool3d k3 s2 p1 count_include_pad=False: z(64,36,72,72) -> xd(64,18,36,36)
__global__ __launch_bounds__(256) void k_pool(const in_t* __restrict__ z, float* __restrict__ xd)
{
    int idx = blockIdx.x*256 + threadIdx.x;
    int c  = idx / S2;
    int r  = idx - c*S2;
    int od = r / W2;
    int r2 = r - od*W2;
    int oh = r2 / 36;
    int ow = r2 - oh*36;
    int dlo = max(2*od-1, 0), dhi = min(2*od+1, 35);
    int hlo = max(2*oh-1, 0), hhi = min(2*oh+1, 71);
    int wlo = max(2*ow-1, 0), whi = min(2*ow+1, 71);
    int cnt = (dhi-dlo+1)*(hhi-hlo+1)*(whi-wlo+1);
    const in_t* zc = z + c*S1;
    float s = 0.f;
    for (int d = dlo; d <= dhi; ++d)
        for (int h = hlo; h <= hhi; ++h)
            for (int w = wlo; w <= whi; ++w)
                s += zc[d*W1 + h*72 + w];
    xd[idx] = s / (float)cnt;
}

// ---- M[c,k1,k2] = sum_m Uxd[c,k1,m]*Uy[c,k2,m]; output bf16 zero-padded [c][96][96]
// grid = 64ch x 3(k1-group) x 3(k2-group) = 576; 243 active threads, 3 acc each
__global__ __launch_bounds__(256) void k_M(
    const float* __restrict__ xd, const float* __restrict__ yk, unsigned short* __restrict__ Mg)
{
    __shared__ float xl[3*LDSTR];
    __shared__ float yl[3*LDSTR];
    int b = blockIdx.x;
    int c = b / 9, r = b - c*9;
    int g = r / 3, h = r - g*3;
    int t = threadIdx.x;
    int t1 = t / 27, t2 = t - (t/27)*27;
    int offx[3];
    #pragma unroll
    for (int a = 0; a < 3; ++a) {
        int kl = t1*3 + a;
        offx[a] = (kl/9)*LDSTR + (kl - (kl/9)*9);
    }
    int offy = (t2/9)*LDSTR + (t2 - (t2/9)*9);
    float acc[3] = {};
    for (int ph2 = 0; ph2 < 2; ++ph2) {
        __syncthreads();
        for (int idx = t; idx < 3*W2; idx += 256) {
            int rr = idx / W2, col = idx - rr*W2;
            xl[rr*LDSTR + col] = xd[c*S2 + (ph2*9 + g*3 + rr)*W2 + col];
            yl[rr*LDSTR + col] = yk[c*S2 + (ph2*9 + h*3 + rr)*W2 + col];
        }
        __syncthreads();
        if (t < 243) {
            for (int m = 0; m < 144; ++m) {
                int cb = m*9;
                float yv = yl[cb + offy];
                #pragma unroll
                for (int a = 0; a < 3; ++a)
                    acc[a] += xl[cb + offx[a]] * yv;
            }
        }
    }
    if (t < 243) {
        #pragma unroll
        for (int a = 0; a < 3; ++a) {
            int k1 = g*27 + t1*3 + a;
            Mg[c*9216 + k1*96 + (h*27 + t2)] = f2bu(acc[a]);
        }
    }
    // zero pads once per channel (rows 81..95 full; cols 81..95 of rows 0..80)
    if (r == 0) {
        for (int idx = t; idx < 2655; idx += 256) {
            int row, col;
            if (idx < 1440) { int q = idx/96; row = 81 + q; col = idx - q*96; }
            else { int j = idx - 1440; int q = j/15; row = q; col = 81 + (j - q*15); }
            Mg[c*9216 + row*96 + col] = 0;
        }
    }
}

// ---- MFMA corr: per (channel, 192-patch chunk): C(96x192) = Mg(96x96,bf16) x Uxq^T
// grid = 64ch * 4ph * 3ck = 768 blocks, 256 threads (4 waves); A-frags from global
__global__ __launch_bounds__(256, 3) void k_corr(
    const unsigned short* __restrict__ Mg, const bf16* __restrict__ xq,
    const in_t* __restrict__ z, out_t* __restrict__ out)
{
    __shared__ __align__(16) unsigned short Pl[192*BSTR];   // 39936 B
    int bid = blockIdx.x;
    int c   = bid / 12;
    int rem = bid - c*12;
    int ph  = rem / 3;
    int ck  = rem - ph*3;
    int colbase = ck*1728;
    int t = threadIdx.x;

    // zero pad cols 81..95 (disjoint from data fill -> no barrier between)
    for (int idx = t; idx < 192*15; idx += 256) {
        int r = idx/15;
        Pl[r*BSTR + 81 + (idx - r*15)] = 0;
    }
    // stage xq chunk: 9 rows x 1728 cols -> Pl[patch][i2*9+j2]
    const unsigned short* xqu =
        (const unsigned short*)(xq + (size_t)c*S1 + (size_t)(ph*9)*W1 + colbase);
    for (int idx = t; idx < 3888; idx += 256) {    // 9*432 ushort4 loads
        int i2 = idx / 432, v4 = idx - i2*432;
        ushort4 vv = *reinterpret_cast<const ushort4*>(xqu + (size_t)i2*W1 + v4*4);
        int col = v4*4;
        unsigned short uu[4] = {vv.x, vv.y, vv.z, vv.w};
        #pragma unroll
        for (int j = 0; j < 4; ++j) {
            int cc = col + j;
            int p = cc/9, j2 = cc - p*9;
            Pl[p*BSTR + i2*9 + j2] = uu[j];
        }
    }
    __syncthreads();

    int wv = t >> 6, l = t & 63;
    int lrow = l & 15, lhi = l >> 4;

    // B fragments: wave wv owns n-tiles wv*3 .. wv*3+2
    short8 bfr[3][3];
    #pragma unroll
    for (int ntl = 0; ntl < 3; ++ntl) {
        int n = (wv*3 + ntl)*16 + lrow;
        #pragma unroll
        for (int kk = 0; kk < 3; ++kk)
            bfr[ntl][kk] = *reinterpret_cast<const short8*>(&Pl[n*BSTR + kk*32 + lhi*8]);
    }

    f32x4 acc[6][3];
    #pragma unroll
    for (int mt = 0; mt < 6; ++mt)
        #pragma unroll
        for (int ntl = 0; ntl < 3; ++ntl)
            acc[mt][ntl] = (f32x4){0.f,0.f,0.f,0.f};

    const unsigned short* Mc = Mg + c*9216;
    #pragma unroll
    for (int mt = 0; mt < 6; ++mt) {
        short8 afr[3];
        #pragma unroll
        for (int kk = 0; kk < 3; ++kk)
            afr[kk] = *reinterpret_cast<const short8*>(Mc + (mt*16 + lrow)*96 + kk*32 + lhi*8);
        #pragma unroll
        for (int ntl = 0; ntl < 3; ++ntl) {
            f32x4 d = acc[mt][ntl];
            #pragma unroll
            for (int kk = 0; kk < 3; ++kk)
                d = __builtin_amdgcn_mfma_f32_16x16x32_bf16(afr[kk], bfr[ntl][kk], d, 0, 0, 0);
            acc[mt][ntl] = d;
        }
    }
    __syncthreads();   // all waves done reading Pl

    // epilogue: 2 passes of 96 patches via LDS staging (9 x 864 fp32 = 31104B)
    float* stage = reinterpret_cast<float*>(Pl);
    #pragma unroll
    for (int pass = 0; pass < 2; ++pass) {
        if ((wv >> 1) == pass) {
            #pragma unroll
            for (int mt = 0; mt < 6; ++mt)
                #pragma unroll
                for (int ntl = 0; ntl < 3; ++ntl) {
                    int n = (wv*3 + ntl)*16 + lrow - pass*96;   // 0..95
                    #pragma unroll
                    for (int r = 0; r < 4; ++r) {
                        int m = mt*16 + lhi*4 + r;              // k1
                        if (m <= 80) {
                            int i = m/9, j = m - 9*i;
                            stage[i*864 + n*9 + j] = acc[mt][ntl][r];
                        }
                    }
                }
        }
        __syncthreads();
        for (int idx = t; idx < 1944; idx += 256) {             // float4 streaming
            int i = idx/216, c4 = idx - i*216;
            float4 sv = *reinterpret_cast<const float4*>(&stage[i*864 + c4*4]);
            int ga = c*S1 + (ph*9 + i)*W1 + colbase + pass*864 + c4*4;
            float4 dv = *reinterpret_cast<const float4*>(&z[ga]);
            float4 ov;
            float cr;
            cr = sv.x*INV_NZ; ov.x = dv.x + (cr > 0.f ? cr : 0.2f*cr)*dv.x;
            cr = sv.y*INV_NZ; ov.y = dv.y + (cr > 0.f ? cr : 0.2f*cr)*dv.y;
            cr = sv.z*INV_NZ; ov.z = dv.z + (cr > 0.f ? cr : 0.2f*cr)*dv.z;
            cr = sv.w*INV_NZ; ov.w = dv.w + (cr > 0.f ? cr : 0.2f*cr)*dv.w;
            *reinterpret_cast<float4*>(&out[ga]) = ov;
        }
        __syncthreads();
    }
}

extern "C" void kernel_launch(void* const* d_in, const int* in_sizes, int n_in,
                              void* d_out, int out_size, void* d_ws, size_t ws_size,
                              hipStream_t stream)
{
    (void)in_sizes; (void)n_in; (void)out_size; (void)ws_size;
    const in_t* x     = (const in_t*)d_in[0];
    const in_t* y     = (const in_t*)d_in[1];
    const in_t* z     = (const in_t*)d_in[2];
    const in_t* w_img = (const in_t*)d_in[3];
    const in_t* b_img = (const in_t*)d_in[4];
    const in_t* w_fea = (const in_t*)d_in[5];
    const in_t* b_fea = (const in_t*)d_in[6];
    out_t* out = (out_t*)d_out;

    char* ws = (char*)d_ws;
    bf16*           xq = (bf16*)          (ws + 0);          // 64*186624*2 = 23,887,872
    float*          yk = (float*)         (ws + 23887872);   // 5,971,968
    float*          xd = (float*)         (ws + 29859840);   // 5,971,968
    unsigned short* Mg = (unsigned short*)(ws + 35831808);   // 64*96*96*2 = 1,179,648

    hipLaunchKernelGGL(k_proj_x, dim3(S1/256),      dim3(256), 0, stream, x, w_img, b_img, xq);
    hipLaunchKernelGGL(k_proj_y, dim3(512),         dim3(256), 0, stream, y, w_fea, b_fea, yk);
    hipLaunchKernelGGL(k_pool,   dim3((CH*S2)/256), dim3(256), 0, stream, z, xd);
    hipLaunchKernelGGL(k_M,      dim3(576),         dim3(256), 0, stream, xd, yk, Mg);
    hipLaunchKernelGGL(k_corr,   dim3(768),         dim3(256), 0, stream, Mg, xq, z, out);
}

// Round 6
// 123.737 us; speedup vs baseline: 1.8796x; 1.0853x over previous
//
#include <hip/hip_runtime.h>
#include <hip/hip_bf16.h>

typedef __hip_bfloat16 bf16;
typedef float in_t;
typedef float out_t;
typedef __attribute__((ext_vector_type(8))) short short8;   // 8 bf16 MFMA operand
typedef __attribute__((ext_vector_type(4))) float f32x4;    // MFMA accumulator

#define CH    64
#define CIN1  32
#define CIN2  64
#define S1    186624   // 36*72*72
#define W1    5184     // 72*72
#define S2    23328    // 18*36*36
#define W2    1296     // 36*36
#define LDSTR 1297     // k_M LDS row stride (coprime with 32)
#define BSTR  104      // k_corr patch lds bf16 row stride
#define PSTR  38       // k_pool LDS row stride (even -> float2 writes aligned)
#define INV_NZ (1.0f/(288.0f + 1e-5f))

static __device__ __forceinline__ unsigned short f2bu(float f) {
    bf16 h = __float2bfloat16(f);
    unsigned short u;
    __builtin_memcpy(&u, &h, 2);
    return u;
}

// ---- xq[o,s] = b[o] + sum_c w[o,c]*x[c,s]; 4 s per thread, float4 in / short4 out
__global__ __launch_bounds__(256) void k_proj_x(
    const in_t* __restrict__ x, const in_t* __restrict__ w, const in_t* __restrict__ bias,
    bf16* __restrict__ xq)
{
    int f = blockIdx.x*256 + threadIdx.x;     // float4 index, S1/4 = 46656 total
    if (f >= S1/4) return;
    const float4* x4 = reinterpret_cast<const float4*>(x);
    float4 xv[CIN1];
    #pragma unroll
    for (int c = 0; c < CIN1; ++c) xv[c] = x4[c*(S1/4) + f];
    ushort4* xq4 = reinterpret_cast<ushort4*>(xq);
    #pragma unroll 4
    for (int o = 0; o < CH; ++o) {
        float b = bias[o];
        float4 a = {b, b, b, b};
        #pragma unroll
        for (int c = 0; c < CIN1; ++c) {
            float wv = w[o*CIN1 + c];          // uniform -> s_load
            a.x += wv*xv[c].x; a.y += wv*xv[c].y;
            a.z += wv*xv[c].z; a.w += wv*xv[c].w;
        }
        ushort4 r = { f2bu(a.x), f2bu(a.y), f2bu(a.z), f2bu(a.w) };
        xq4[o*(S1/4) + f] = r;
    }
}

// ---- yk: 512 blocks = 32 o-pairs x 16 spatial chunks of 1458
__global__ __launch_bounds__(256) void k_proj_y(
    const in_t* __restrict__ y, const in_t* __restrict__ w, const in_t* __restrict__ bias,
    float* __restrict__ yk)
{
    int bid   = blockIdx.x;
    int o0    = (bid >> 4) * 2;
    int chunk = bid & 15;
    int t = threadIdx.x;
    float b0 = bias[o0], b1 = bias[o0+1];
    for (int it = 0; it < 6; ++it) {
        int sl = it*256 + t;
        if (sl >= 1458) break;
        int s = chunk*1458 + sl;
        float a0 = b0, a1 = b1;
        #pragma unroll
        for (int cc = 0; cc < CIN2; ++cc) {
            float yv = y[cc*S2 + s];
            a0 += w[o0*CIN2 + cc]     * yv;
            a1 += w[(o0+1)*CIN2 + cc] * yv;
        }
        yk[o0*S2 + s]     = a0;
        yk[(o0+1)*S2 + s] = a1;
    }
}

// ---- AvgPool3d k3 s2 p1, count_include_pad=False, separable via LDS
// grid = 64ch * 18 od = 1152 blocks
__global__ __launch_bounds__(256) void k_pool(const in_t* __restrict__ z, float* __restrict__ xd)
{
    __shared__ float wp[3*72*PSTR];           // w-pooled rows, 32832 B
    int bid = blockIdx.x;
    int c  = bid / 18, od = bid - (bid/18)*18;
    int t = threadIdx.x;
    // load + w-pool: 216 (dd,h) rows; each thread streams one row of 72 w as 18 float4
    for (int row = t; row < 216; row += 256) {
        int dd = row / 72, h = row - (row/72)*72;
        int d  = 2*od - 1 + dd;
        float* wrow = &wp[(dd*72 + h)*PSTR];
        if (d < 0) {                          // only od==0, dd==0 (pad plane)
            #pragma unroll
            for (int q = 0; q < 18; ++q)
                *reinterpret_cast<float2*>(&wrow[2*q]) = (float2){0.f, 0.f};
        } else {
            const float4* zr = reinterpret_cast<const float4*>(
                z + ((size_t)(c*36 + d))*W1 + (size_t)h*72);
            float carry = 0.f;
            #pragma unroll
            for (int q = 0; q < 18; ++q) {
                float4 u = zr[q];
                float s0 = carry + u.x + u.y; // ow=2q   (w = 4q-1,4q,4q+1)
                float s1 = u.y + u.z + u.w;   // ow=2q+1 (w = 4q+1..4q+3)
                carry = u.w;
                *reinterpret_cast<float2*>(&wrow[2*q]) = (float2){s0, s1};
            }
        }
    }
    __syncthreads();
    // h+d pool from LDS: 1296 outputs
    int base_out = c*S2 + od*W2;
    for (int idx = t; idx < 1296; idx += 256) {
        int oh = idx / 36, ow = idx - (idx/36)*36;
        int hlo = (2*oh - 1 < 0) ? 0 : 2*oh - 1;
        int hhi = 2*oh + 1;                   // <= 71 always
        float s = 0.f;
        for (int h = hlo; h <= hhi; ++h)
            s += wp[h*PSTR + ow] + wp[(72 + h)*PSTR + ow] + wp[(144 + h)*PSTR + ow];
        int cd = (od == 0) ? 2 : 3;
        int chh = (oh == 0) ? 2 : 3;
        int cw = (ow == 0) ? 2 : 3;
        xd[base_out + idx] = s / (float)(cd*chh*cw);
    }
}

// ---- M[c,k1,k2] = sum_m Uxd[c,k1,m]*Uy[c,k2,m]; output bf16 zero-padded [c][96][96]
// grid = 64ch x 3(k1-group) x 3(k2-group) = 576; 243 active threads, 3 acc each
__global__ __launch_bounds__(256) void k_M(
    const float* __restrict__ xd, const float* __restrict__ yk, unsigned short* __restrict__ Mg)
{
    __shared__ float xl[3*LDSTR];
    __shared__ float yl[3*LDSTR];
    int b = blockIdx.x;
    int c = b / 9, r = b - c*9;
    int g = r / 3, h = r - g*3;
    int t = threadIdx.x;
    int t1 = t / 27, t2 = t - (t/27)*27;
    int offx[3];
    #pragma unroll
    for (int a = 0; a < 3; ++a) {
        int kl = t1*3 + a;
        offx[a] = (kl/9)*LDSTR + (kl - (kl/9)*9);
    }
    int offy = (t2/9)*LDSTR + (t2 - (t2/9)*9);
    float acc[3] = {};
    for (int ph2 = 0; ph2 < 2; ++ph2) {
        __syncthreads();
        for (int idx = t; idx < 3*W2; idx += 256) {
            int rr = idx / W2, col = idx - rr*W2;
            xl[rr*LDSTR + col] = xd[c*S2 + (ph2*9 + g*3 + rr)*W2 + col];
            yl[rr*LDSTR + col] = yk[c*S2 + (ph2*9 + h*3 + rr)*W2 + col];
        }
        __syncthreads();
        if (t < 243) {
            for (int m = 0; m < 144; ++m) {
                int cb = m*9;
                float yv = yl[cb + offy];
                #pragma unroll
                for (int a = 0; a < 3; ++a)
                    acc[a] += xl[cb + offx[a]] * yv;
            }
        }
    }
    if (t < 243) {
        #pragma unroll
        for (int a = 0; a < 3; ++a) {
            int k1 = g*27 + t1*3 + a;
            Mg[c*9216 + k1*96 + (h*27 + t2)] = f2bu(acc[a]);
        }
    }
    // zero pads once per channel (rows 81..95 full; cols 81..95 of rows 0..80)
    if (r == 0) {
        for (int idx = t; idx < 2655; idx += 256) {
            int row, col;
            if (idx < 1440) { int q = idx/96; row = 81 + q; col = idx - q*96; }
            else { int j = idx - 1440; int q = j/15; row = q; col = 81 + (j - q*15); }
            Mg[c*9216 + row*96 + col] = 0;
        }
    }
}

// ---- MFMA corr: per (channel, 192-patch chunk): C(96x192) = Mg(96x96,bf16) x Uxq^T
// grid = 64ch * 4ph * 3ck = 768 blocks, 256 threads (4 waves); A-frags from global
__global__ __launch_bounds__(256, 3) void k_corr(
    const unsigned short* __restrict__ Mg, const bf16* __restrict__ xq,
    const in_t* __restrict__ z, out_t* __restrict__ out)
{
    __shared__ __align__(16) unsigned short Pl[192*BSTR];   // 39936 B
    int bid = blockIdx.x;
    int c   = bid / 12;
    int rem = bid - c*12;
    int ph  = rem / 3;
    int ck  = rem - ph*3;
    int colbase = ck*1728;
    int t = threadIdx.x;

    // zero pad cols 81..95 (disjoint from data fill -> no barrier between)
    for (int idx = t; idx < 192*15; idx += 256) {
        int r = idx/15;
        Pl[r*BSTR + 81 + (idx - r*15)] = 0;
    }
    // stage xq chunk: 9 rows x 1728 cols -> Pl[patch][i2*9+j2]
    const unsigned short* xqu =
        (const unsigned short*)(xq + (size_t)c*S1 + (size_t)(ph*9)*W1 + colbase);
    for (int idx = t; idx < 3888; idx += 256) {    // 9*432 ushort4 loads
        int i2 = idx / 432, v4 = idx - i2*432;
        ushort4 vv = *reinterpret_cast<const ushort4*>(xqu + (size_t)i2*W1 + v4*4);
        int col = v4*4;
        unsigned short uu[4] = {vv.x, vv.y, vv.z, vv.w};
        #pragma unroll
        for (int j = 0; j < 4; ++j) {
            int cc = col + j;
            int p = cc/9, j2 = cc - p*9;
            Pl[p*BSTR + i2*9 + j2] = uu[j];
        }
    }
    __syncthreads();

    int wv = t >> 6, l = t & 63;
    int lrow = l & 15, lhi = l >> 4;

    // B fragments: wave wv owns n-tiles wv*3 .. wv*3+2
    short8 bfr[3][3];
    #pragma unroll
    for (int ntl = 0; ntl < 3; ++ntl) {
        int n = (wv*3 + ntl)*16 + lrow;
        #pragma unroll
        for (int kk = 0; kk < 3; ++kk)
            bfr[ntl][kk] = *reinterpret_cast<const short8*>(&Pl[n*BSTR + kk*32 + lhi*8]);
    }

    f32x4 acc[6][3];
    #pragma unroll
    for (int mt = 0; mt < 6; ++mt)
        #pragma unroll
        for (int ntl = 0; ntl < 3; ++ntl)
            acc[mt][ntl] = (f32x4){0.f,0.f,0.f,0.f};

    const unsigned short* Mc = Mg + c*9216;
    #pragma unroll
    for (int mt = 0; mt < 6; ++mt) {
        short8 afr[3];
        #pragma unroll
        for (int kk = 0; kk < 3; ++kk)
            afr[kk] = *reinterpret_cast<const short8*>(Mc + (mt*16 + lrow)*96 + kk*32 + lhi*8);
        #pragma unroll
        for (int ntl = 0; ntl < 3; ++ntl) {
            f32x4 d = acc[mt][ntl];
            #pragma unroll
            for (int kk = 0; kk < 3; ++kk)
                d = __builtin_amdgcn_mfma_f32_16x16x32_bf16(afr[kk], bfr[ntl][kk], d, 0, 0, 0);
            acc[mt][ntl] = d;
        }
    }
    __syncthreads();   // all waves done reading Pl

    // epilogue: 2 passes of 96 patches via LDS staging (9 x 864 fp32 = 31104B)
    float* stage = reinterpret_cast<float*>(Pl);
    #pragma unroll
    for (int pass = 0; pass < 2; ++pass) {
        if ((wv >> 1) == pass) {
            #pragma unroll
            for (int mt = 0; mt < 6; ++mt)
                #pragma unroll
                for (int ntl = 0; ntl < 3; ++ntl) {
                    int n = (wv*3 + ntl)*16 + lrow - pass*96;   // 0..95
                    #pragma unroll
                    for (int r = 0; r < 4; ++r) {
                        int m = mt*16 + lhi*4 + r;              // k1
                        if (m <= 80) {
                            int i = m/9, j = m - 9*i;
                            stage[i*864 + n*9 + j] = acc[mt][ntl][r];
                        }
                    }
                }
        }
        __syncthreads();
        for (int idx = t; idx < 1944; idx += 256) {             // float4 streaming
            int i = idx/216, c4 = idx - i*216;
            float4 sv = *reinterpret_cast<const float4*>(&stage[i*864 + c4*4]);
            int ga = c*S1 + (ph*9 + i)*W1 + colbase + pass*864 + c4*4;
            float4 dv = *reinterpret_cast<const float4*>(&z[ga]);
            float4 ov;
            float cr;
            cr = sv.x*INV_NZ; ov.x = dv.x + (cr > 0.f ? cr : 0.2f*cr)*dv.x;
            cr = sv.y*INV_NZ; ov.y = dv.y + (cr > 0.f ? cr : 0.2f*cr)*dv.y;
            cr = sv.z*INV_NZ; ov.z = dv.z + (cr > 0.f ? cr : 0.2f*cr)*dv.z;
            cr = sv.w*INV_NZ; ov.w = dv.w + (cr > 0.f ? cr : 0.2f*cr)*dv.w;
            *reinterpret_cast<float4*>(&out[ga]) = ov;
        }
        __syncthreads();
    }
}

extern "C" void kernel_launch(void* const* d_in, const int* in_sizes, int n_in,
                              void* d_out, int out_size, void* d_ws, size_t ws_size,
                              hipStream_t stream)
{
    (void)in_sizes; (void)n_in; (void)out_size; (void)ws_size;
    const in_t* x     = (const in_t*)d_in[0];
    const in_t* y     = (const in_t*)d_in[1];
    const in_t* z     = (const in_t*)d_in[2];
    const in_t* w_img = (const in_t*)d_in[3];
    const in_t* b_img = (const in_t*)d_in[4];
    const in_t* w_fea = (const in_t*)d_in[5];
    const in_t* b_fea = (const in_t*)d_in[6];
    out_t* out = (out_t*)d_out;

    char* ws = (char*)d_ws;
    bf16*           xq = (bf16*)          (ws + 0);          // 23,887,872
    float*          yk = (float*)         (ws + 23887872);   // 5,971,968
    float*          xd = (float*)         (ws + 29859840);   // 5,971,968
    unsigned short* Mg = (unsigned short*)(ws + 35831808);   // 1,179,648

    hipLaunchKernelGGL(k_proj_x, dim3(183),  dim3(256), 0, stream, x, w_img, b_img, xq);
    hipLaunchKernelGGL(k_proj_y, dim3(512),  dim3(256), 0, stream, y, w_fea, b_fea, yk);
    hipLaunchKernelGGL(k_pool,   dim3(1152), dim3(256), 0, stream, z, xd);
    hipLaunchKernelGGL(k_M,      dim3(576),  dim3(256), 0, stream, xd, yk, Mg);
    hipLaunchKernelGGL(k_corr,   dim3(768),  dim3(256), 0, stream, Mg, xq, z, out);
}